// Round 9
// baseline (435.980 us; speedup 1.0000x reference)
//
#include <hip/hip_runtime.h>

#define NN 50000
#define EE 800000
#define DD 64
#define GG 512
#define TILES 782          // ceil(NN/64)
#define SCAN_BLOCKS 98     // ceil(NN/512)
#define TS 68              // LDS tile stride: 16B-aligned rows

// ---- bf16 helpers ----
__device__ __forceinline__ float b2f(unsigned short u) {
    union { unsigned int i; float f; } c;
    c.i = ((unsigned int)u) << 16;
    return c.f;
}
__device__ __forceinline__ unsigned short f2b(float f) {
    union { float f; unsigned int i; } c;
    c.f = f;
    const unsigned int r = c.i + 0x7FFFu + ((c.i >> 16) & 1u);  // rne
    return (unsigned short)(r >> 16);
}
__device__ __forceinline__ int rfl(int v) { return __builtin_amdgcn_readfirstlane(v); }

// ===========================================================================
// CSR build: histogram -> 2-level exclusive scan -> XCD-partitioned fill.
// ===========================================================================
__global__ __launch_bounds__(256) void hist_kernel(const int* __restrict__ ei,
                                                   int* __restrict__ counts) {
    const int e = blockIdx.x * blockDim.x + threadIdx.x;
    if (e < EE) atomicAdd(&counts[ei[EE + e]], 1);
}

__global__ __launch_bounds__(512) void scan1_kernel(const int* __restrict__ counts,
                                                    int* __restrict__ scanned,
                                                    int* __restrict__ bsum) {
    __shared__ int buf[512];
    const int i = blockIdx.x * 512 + threadIdx.x;
    const int v = (i < NN) ? counts[i] : 0;
    buf[threadIdx.x] = v;
    __syncthreads();
    for (int off = 1; off < 512; off <<= 1) {
        const int add = (threadIdx.x >= off) ? buf[threadIdx.x - off] : 0;
        __syncthreads();
        buf[threadIdx.x] += add;
        __syncthreads();
    }
    if (i < NN) scanned[i] = buf[threadIdx.x] - v;   // exclusive
    if (threadIdx.x == 511) bsum[blockIdx.x] = buf[511];
}

__global__ __launch_bounds__(512) void scan2_kernel(const int* __restrict__ scanned,
                                                    const int* __restrict__ bsum,
                                                    int* __restrict__ rowptr,
                                                    int* __restrict__ cursor) {
    __shared__ int red[128];
    if (threadIdx.x < 128)
        red[threadIdx.x] = (threadIdx.x < blockIdx.x) ? bsum[threadIdx.x] : 0;
    __syncthreads();
    for (int off = 64; off > 0; off >>= 1) {
        if (threadIdx.x < off) red[threadIdx.x] += red[threadIdx.x + off];
        __syncthreads();
    }
    const int offset = red[0];
    const int i = blockIdx.x * 512 + threadIdx.x;
    if (i < NN) {
        const int p = scanned[i] + offset;
        rowptr[i] = p;
        cursor[i] = p;
    }
    if (blockIdx.x == 0 && threadIdx.x == 0) rowptr[NN] = EE;
}

// XCD-class partitioned fill: block b handles edge chunk (b>>3), class (b&7).
// Only edges with dst/6250 == class are written -> each col/cursor region is
// written by one block-class (one XCD under round-robin dispatch), so lines
// are fully dirtied in-cache before eviction (round-8: scattered cross-XCD
// 4B writes caused 52 MB of partial-line writebacks).
__global__ __launch_bounds__(256) void fill_kernel(const int* __restrict__ ei,
                                                   int* __restrict__ cursor,
                                                   int* __restrict__ col) {
    const int cls = blockIdx.x & 7;
    const int chunk = blockIdx.x >> 3;              // 0..255
    const int e0 = chunk * 3125;                    // 256*3125 == EE
    for (int e = e0 + threadIdx.x; e < e0 + 3125; e += 256) {
        const int dst = ei[EE + e];
        if (dst / 6250 == cls) {
            const int pos = atomicAdd(&cursor[dst], 1);
            col[pos] = ei[e];
        }
    }
}

// ===========================================================================
// fp32 -> bf16 conversion (x staged once)
// ===========================================================================
__global__ __launch_bounds__(256) void tobf_kernel(const float* __restrict__ in,
                                                   unsigned short* __restrict__ out,
                                                   const int n4) {
    const int i = blockIdx.x * 256 + threadIdx.x;
    if (i >= n4) return;
    const float4 v = ((const float4*)in)[i];
    ushort4 o;
    o.x = f2b(v.x); o.y = f2b(v.y); o.z = f2b(v.z); o.w = f2b(v.w);
    ((ushort4*)out)[i] = o;
}

// ===========================================================================
// Gather: one wave per row, lane = feature. BN finalize of the previous layer
// folded into the preamble (reads 8x128 stats, computes scl/sft per lane).
// Fast path deg<=32: ONE predicated 32-deep batch -> one vmcnt drain per row
// (was two), 32 loads in flight. Rare deg>32 falls back to the 16-batch loop.
// z = scl.*(h_self + sum_nbr h) + (deg+1).*sft
// ===========================================================================
__global__ __launch_bounds__(256, 4) void gather_kernel(const unsigned short* __restrict__ hin,
                                                        const int* __restrict__ rowptr,
                                                        const int* __restrict__ col,
                                                        const float* __restrict__ stats,
                                                        const float* __restrict__ ga,
                                                        const float* __restrict__ be,
                                                        const int apply,
                                                        float* __restrict__ z) {
    const int wv = (blockIdx.x * 256 + threadIdx.x) >> 6;
    const int lane = threadIdx.x & 63;
    const int nwaves = (gridDim.x * 256) >> 6;

    float scl = 1.0f, sft = 0.0f;
    if (apply) {   // fold finalize: reduce per-layer stats -> scale/shift
        float s = 0.f, sq = 0.f;
        #pragma unroll
        for (int k = 0; k < 8; ++k) {
            s += stats[k * 128 + lane];
            sq += stats[k * 128 + 64 + lane];
        }
        const float mean = s * (1.0f / NN);
        const float var = sq * (1.0f / NN) - mean * mean;
        scl = ga[lane] * rsqrtf(var + 1e-5f);
        sft = be[lane] - mean * scl;
    }

    for (int row = rfl(wv); row < NN; row += nwaves) {
        const int beg = rfl(rowptr[row]);
        const int end = rfl(rowptr[row + 1]);
        const int deg = end - beg;
        float a[8];
        #pragma unroll
        for (int i = 0; i < 8; ++i) a[i] = 0.f;
        a[0] = b2f(hin[row * 64 + lane]);   // self term

        if (deg <= 32) {
            // single predicated batch, one drain
            const int safeb = (beg < EE) ? beg : 0;
            int c[32];
            #pragma unroll
            for (int i = 0; i < 32; ++i) {
                const int jj = (i < deg) ? (beg + i) : safeb;
                c[i] = rfl(col[jj]);
            }
            float hv[32];
            #pragma unroll
            for (int i = 0; i < 32; ++i) hv[i] = b2f(hin[c[i] * 64 + lane]);
            #pragma unroll
            for (int i = 0; i < 32; ++i) a[i & 7] += (i < deg) ? hv[i] : 0.f;
        } else {
            int j = beg;
            for (; j + 16 <= end; j += 16) {
                int c[16];
                #pragma unroll
                for (int i = 0; i < 16; ++i) c[i] = rfl(col[j + i]);
                float hv[16];
                #pragma unroll
                for (int i = 0; i < 16; ++i) hv[i] = b2f(hin[c[i] * 64 + lane]);
                #pragma unroll
                for (int i = 0; i < 16; ++i) a[i & 7] += hv[i];
            }
            if (j < end) {
                int c[16];
                #pragma unroll
                for (int i = 0; i < 16; ++i) {
                    const int jj = (j + i < end) ? (j + i) : beg;
                    c[i] = rfl(col[jj]);
                }
                float hv[16];
                #pragma unroll
                for (int i = 0; i < 16; ++i) hv[i] = b2f(hin[c[i] * 64 + lane]);
                #pragma unroll
                for (int i = 0; i < 16; ++i) a[i & 7] += (j + i < end) ? hv[i] : 0.f;
            }
        }
        const float sum = ((a[0] + a[1]) + (a[2] + a[3])) + ((a[4] + a[5]) + (a[6] + a[7]));
        z[row * 64 + lane] = fmaf(sum, scl, (float)(deg + 1) * sft);
    }
}

// ===========================================================================
// MLP: 64-row tile, 512 threads (8 waves). f0 wave-uniform -> s_load weights.
// ===========================================================================
__global__ __launch_bounds__(512) void mlp_kernel(const float* __restrict__ z,
                                                  const float* __restrict__ wa,
                                                  const float* __restrict__ ba,
                                                  const float* __restrict__ wb,
                                                  const float* __restrict__ bb,
                                                  unsigned short* __restrict__ tout,
                                                  float* __restrict__ stats) {
    __shared__ float tile[64 * TS];
    __shared__ float tile2[64 * TS];
    __shared__ float red[8][128];

    const int wave = threadIdx.x >> 6;
    const int lane = threadIdx.x & 63;
    const int row0 = blockIdx.x * 64;
    const int nrows = min(64, NN - row0);

    // ---- p0: stage z tile ----
    #pragma unroll
    for (int m = 0; m < 2; ++m) {
        const int g = m * 512 + threadIdx.x;    // 1024 float4 groups
        const int r = g >> 4;
        const int f = (g & 15) * 4;
        const int grow = row0 + r;
        float4 v = make_float4(0.f, 0.f, 0.f, 0.f);
        if (grow < NN) v = *(const float4*)(z + grow * 64 + f);
        *(float4*)(&tile[r * TS + f]) = v;
    }
    __syncthreads();

    // ---- p1: A-matmul, lane = row, wave owns features f0..f0+7 ----
    const int f0 = rfl(wave * 8);   // provably uniform -> s_load weights
    float acc[8];
    #pragma unroll
    for (int j = 0; j < 8; ++j) acc[j] = ba[f0 + j];
    #pragma unroll 4
    for (int k4 = 0; k4 < 16; ++k4) {
        const float4 v = *(const float4*)(&tile[lane * TS + k4 * 4]);
        #pragma unroll
        for (int j = 0; j < 8; ++j) {
            acc[j] = fmaf(v.x, wa[(k4 * 4 + 0) * 64 + f0 + j], acc[j]);
            acc[j] = fmaf(v.y, wa[(k4 * 4 + 1) * 64 + f0 + j], acc[j]);
            acc[j] = fmaf(v.z, wa[(k4 * 4 + 2) * 64 + f0 + j], acc[j]);
            acc[j] = fmaf(v.w, wa[(k4 * 4 + 3) * 64 + f0 + j], acc[j]);
        }
    }
    #pragma unroll
    for (int j = 0; j < 8; j += 4) {
        float4 o;
        o.x = fmaxf(acc[j + 0], 0.f);
        o.y = fmaxf(acc[j + 1], 0.f);
        o.z = fmaxf(acc[j + 2], 0.f);
        o.w = fmaxf(acc[j + 3], 0.f);
        *(float4*)(&tile2[lane * TS + f0 + j]) = o;
    }
    __syncthreads();

    // ---- p2: B-matmul -> raw t into tile ----
    #pragma unroll
    for (int j = 0; j < 8; ++j) acc[j] = bb[f0 + j];
    #pragma unroll 4
    for (int k4 = 0; k4 < 16; ++k4) {
        const float4 v = *(const float4*)(&tile2[lane * TS + k4 * 4]);
        #pragma unroll
        for (int j = 0; j < 8; ++j) {
            acc[j] = fmaf(v.x, wb[(k4 * 4 + 0) * 64 + f0 + j], acc[j]);
            acc[j] = fmaf(v.y, wb[(k4 * 4 + 1) * 64 + f0 + j], acc[j]);
            acc[j] = fmaf(v.z, wb[(k4 * 4 + 2) * 64 + f0 + j], acc[j]);
            acc[j] = fmaf(v.w, wb[(k4 * 4 + 3) * 64 + f0 + j], acc[j]);
        }
    }
    #pragma unroll
    for (int j = 0; j < 8; j += 4) {
        float4 o;
        o.x = fmaxf(acc[j + 0], 0.f);
        o.y = fmaxf(acc[j + 1], 0.f);
        o.z = fmaxf(acc[j + 2], 0.f);
        o.w = fmaxf(acc[j + 3], 0.f);
        *(float4*)(&tile[lane * TS + f0 + j]) = o;
    }
    __syncthreads();

    // ---- p3a: BN partials ----
    {
        const int rbeg = wave * 8;
        const int rend = min(rbeg + 8, nrows);
        float s = 0.f, sq = 0.f;
        for (int r = rbeg; r < rend; ++r) {
            const float v = tile[r * TS + lane];
            s += v;
            sq += v * v;
        }
        red[wave][lane] = s;
        red[wave][64 + lane] = sq;
    }
    __syncthreads();
    if (threadIdx.x < 128) {
        float tot = 0.f;
        #pragma unroll
        for (int w = 0; w < 8; ++w) tot += red[w][threadIdx.x];
        atomicAdd(&stats[(blockIdx.x & 7) * 128 + threadIdx.x], tot);
    }

    // ---- p3b: bf16 writeback ----
    #pragma unroll
    for (int m = 0; m < 2; ++m) {
        const int g = m * 512 + threadIdx.x;
        const int r = g >> 4;
        const int f = (g & 15) * 4;
        const int grow = row0 + r;
        if (grow < NN) {
            const float4 v = *(const float4*)(&tile[r * TS + f]);
            ushort4 o;
            o.x = f2b(v.x); o.y = f2b(v.y); o.z = f2b(v.z); o.w = f2b(v.w);
            *(ushort4*)(tout + grow * 64 + f) = o;
        }
    }
}

// ===========================================================================
// Pool (bf16 t in, layer-3 BN finalize folded into preamble); batch sorted.
// ===========================================================================
__global__ __launch_bounds__(256) void pool_kernel(const unsigned short* __restrict__ t,
                                                   const int* __restrict__ batch,
                                                   const float* __restrict__ stats,
                                                   const float* __restrict__ ga,
                                                   const float* __restrict__ be,
                                                   float* __restrict__ xpool) {
    const int wv = (blockIdx.x * 256 + threadIdx.x) >> 6;
    const int lane = threadIdx.x & 63;

    float s = 0.f, sq = 0.f;
    #pragma unroll
    for (int k = 0; k < 8; ++k) {
        s += stats[k * 128 + lane];
        sq += stats[k * 128 + 64 + lane];
    }
    const float mean = s * (1.0f / NN);
    const float var = sq * (1.0f / NN) - mean * mean;
    const float scl = ga[lane] * rsqrtf(var + 1e-5f);
    const float sft = be[lane] - mean * scl;

    const int r0 = wv * 64;
    if (r0 >= NN) return;
    const int r1 = min(r0 + 64, NN);
    int gprev = batch[r0];
    float acc = 0.f;
    for (int r = r0; r < r1; ++r) {
        const int g = batch[r];
        if (g != gprev) {
            __hip_atomic_fetch_add(&xpool[gprev * 64 + lane], acc,
                                   __ATOMIC_RELAXED, __HIP_MEMORY_SCOPE_AGENT);
            acc = 0.f;
            gprev = g;
        }
        acc += fmaf(b2f(t[r * 64 + lane]), scl, sft);
    }
    __hip_atomic_fetch_add(&xpool[gprev * 64 + lane], acc,
                           __ATOMIC_RELAXED, __HIP_MEMORY_SCOPE_AGENT);
}

// ===========================================================================
// Fused head: out[g] = relu((xpool[g] @ w0 + b0) @ w1 + b1). One block per g.
// ===========================================================================
__global__ __launch_bounds__(128) void head_kernel(const float* __restrict__ xpool,
                                                   const float* __restrict__ w0,
                                                   const float* __restrict__ b0,
                                                   const float* __restrict__ w1,
                                                   const float* __restrict__ b1,
                                                   float* __restrict__ out) {
    __shared__ float xp[64];
    __shared__ float midl[128];
    const int g = blockIdx.x;
    const int t = threadIdx.x;
    if (t < 64) xp[t] = xpool[g * 64 + t];
    __syncthreads();
    float acc = b0[t];
    #pragma unroll 8
    for (int k = 0; k < 64; ++k) acc = fmaf(xp[k], w0[k * 128 + t], acc);
    midl[t] = acc;
    __syncthreads();
    if (t < 64) {
        float a2 = b1[t];
        #pragma unroll 8
        for (int k = 0; k < 128; ++k) a2 = fmaf(midl[k], w1[k * 64 + t], a2);
        out[g * 64 + t] = fmaxf(a2, 0.f);
    }
}

extern "C" void kernel_launch(void* const* d_in, const int* in_sizes, int n_in,
                              void* d_out, int out_size, void* d_ws, size_t ws_size,
                              hipStream_t stream) {
    const float* x = (const float*)d_in[0];
    const int* ei = (const int*)d_in[1];
    const int* batch = (const int*)d_in[2];

    // ---- workspace layout ----
    int* ibase   = (int*)d_ws;
    int* counts  = ibase;            // 50000
    int* scanned = ibase + 50000;    // 50000
    int* rowptr  = ibase + 100000;   // 50001 (pad to 50004)
    int* cursor  = ibase + 150004;   // 50000
    int* bsum    = ibase + 200004;   // 128 (98 used)
    int* col     = ibase + 200132;   // 800000 -> int end 1,000,132 (pad 1,000,192)
    float* fbase = (float*)d_ws + 1000192;       // 16B aligned
    float* stats = fbase;                        // 3 x 1024 = 3072
    float* xpool = stats + 3072;                 // 32768
    float* z     = xpool + 32768;                // NN*64 = 3,200,000 fp32
    unsigned short* xbf  = (unsigned short*)(z + 3200000);  // 3.2M ushorts
    unsigned short* t0bf = xbf + 3200000;
    unsigned short* t1bf = t0bf + 3200000;

    // ---- CSR build + zeroing ----
    hipMemsetAsync(counts, 0, 50000 * sizeof(int), stream);
    hipMemsetAsync(stats, 0, (3072 + 32768) * sizeof(float), stream);  // stats + xpool
    hist_kernel<<<(EE + 255) / 256, 256, 0, stream>>>(ei, counts);
    scan1_kernel<<<SCAN_BLOCKS, 512, 0, stream>>>(counts, scanned, bsum);
    scan2_kernel<<<SCAN_BLOCKS, 512, 0, stream>>>(scanned, bsum, rowptr, cursor);
    fill_kernel<<<2048, 256, 0, stream>>>(ei, cursor, col);
    tobf_kernel<<<(800000 + 255) / 256, 256, 0, stream>>>(x, xbf, 800000);

    // ---- 3 GIN layers: gather (latency-shaped) + mlp (compute-shaped) ----
    const unsigned short* hcur = xbf;
    unsigned short* touts[3] = {t0bf, t1bf, t0bf};
    for (int l = 0; l < 3; ++l) {
        const float* wa = (const float*)d_in[3 + l * 6 + 0];
        const float* ba = (const float*)d_in[3 + l * 6 + 1];
        const float* wb = (const float*)d_in[3 + l * 6 + 2];
        const float* bb = (const float*)d_in[3 + l * 6 + 3];
        // previous layer's gamma/beta for the folded finalize (unused on l=0)
        const float* gp = (const float*)d_in[3 + (l ? (l - 1) : 0) * 6 + 4];
        const float* bp = (const float*)d_in[3 + (l ? (l - 1) : 0) * 6 + 5];

        gather_kernel<<<1024, 256, 0, stream>>>(hcur, rowptr, col,
                                                stats + (l ? (l - 1) : 0) * 1024,
                                                gp, bp, l > 0, z);
        mlp_kernel<<<TILES, 512, 0, stream>>>(z, wa, ba, wb, bb, touts[l],
                                              stats + l * 1024);
        hcur = touts[l];
    }

    pool_kernel<<<(TILES + 3) / 4, 256, 0, stream>>>(
        t0bf, batch, stats + 2048,
        (const float*)d_in[19], (const float*)d_in[20], xpool);
    head_kernel<<<GG, 128, 0, stream>>>(
        xpool, (const float*)d_in[21], (const float*)d_in[22],
        (const float*)d_in[23], (const float*)d_in[24], (float*)d_out);
}

// Round 10
// 363.458 us; speedup vs baseline: 1.1995x; 1.1995x over previous
//
#include <hip/hip_runtime.h>

#define NN 50000
#define EE 800000
#define DD 64
#define GG 512
#define TILES 782          // ceil(NN/64)
#define SCAN_BLOCKS 98     // ceil(NN/512)
#define TS 68              // LDS tile stride: 16B-aligned rows

// ---- bf16 helpers ----
__device__ __forceinline__ float b2f(unsigned short u) {
    union { unsigned int i; float f; } c;
    c.i = ((unsigned int)u) << 16;
    return c.f;
}
__device__ __forceinline__ unsigned short f2b(float f) {
    union { float f; unsigned int i; } c;
    c.f = f;
    const unsigned int r = c.i + 0x7FFFu + ((c.i >> 16) & 1u);  // rne
    return (unsigned short)(r >> 16);
}
__device__ __forceinline__ int rfl(int v) { return __builtin_amdgcn_readfirstlane(v); }

// ===========================================================================
// CSR build: histogram -> 2-level exclusive scan -> XCD-partitioned fill.
// ===========================================================================
__global__ __launch_bounds__(256) void hist_kernel(const int* __restrict__ ei,
                                                   int* __restrict__ counts) {
    const int e = blockIdx.x * blockDim.x + threadIdx.x;
    if (e < EE) atomicAdd(&counts[ei[EE + e]], 1);
}

__global__ __launch_bounds__(512) void scan1_kernel(const int* __restrict__ counts,
                                                    int* __restrict__ scanned,
                                                    int* __restrict__ bsum) {
    __shared__ int buf[512];
    const int i = blockIdx.x * 512 + threadIdx.x;
    const int v = (i < NN) ? counts[i] : 0;
    buf[threadIdx.x] = v;
    __syncthreads();
    for (int off = 1; off < 512; off <<= 1) {
        const int add = (threadIdx.x >= off) ? buf[threadIdx.x - off] : 0;
        __syncthreads();
        buf[threadIdx.x] += add;
        __syncthreads();
    }
    if (i < NN) scanned[i] = buf[threadIdx.x] - v;   // exclusive
    if (threadIdx.x == 511) bsum[blockIdx.x] = buf[511];
}

__global__ __launch_bounds__(512) void scan2_kernel(const int* __restrict__ scanned,
                                                    const int* __restrict__ bsum,
                                                    int* __restrict__ rowptr,
                                                    int* __restrict__ cursor) {
    __shared__ int red[128];
    if (threadIdx.x < 128)
        red[threadIdx.x] = (threadIdx.x < blockIdx.x) ? bsum[threadIdx.x] : 0;
    __syncthreads();
    for (int off = 64; off > 0; off >>= 1) {
        if (threadIdx.x < off) red[threadIdx.x] += red[threadIdx.x + off];
        __syncthreads();
    }
    const int offset = red[0];
    const int i = blockIdx.x * 512 + threadIdx.x;
    if (i < NN) {
        const int p = scanned[i] + offset;
        rowptr[i] = p;
        cursor[i] = p;
    }
    if (blockIdx.x == 0 && threadIdx.x == 0) rowptr[NN] = EE;
}

// XCD-class partitioned fill (round-8 fix for 52MB partial-line writebacks).
__global__ __launch_bounds__(256) void fill_kernel(const int* __restrict__ ei,
                                                   int* __restrict__ cursor,
                                                   int* __restrict__ col) {
    const int cls = blockIdx.x & 7;
    const int chunk = blockIdx.x >> 3;              // 0..255
    const int e0 = chunk * 3125;                    // 256*3125 == EE
    for (int e = e0 + threadIdx.x; e < e0 + 3125; e += 256) {
        const int dst = ei[EE + e];
        if (dst / 6250 == cls) {
            const int pos = atomicAdd(&cursor[dst], 1);
            col[pos] = ei[e];
        }
    }
}

// ===========================================================================
// fp32 -> bf16 conversion (x staged once)
// ===========================================================================
__global__ __launch_bounds__(256) void tobf_kernel(const float* __restrict__ in,
                                                   unsigned short* __restrict__ out,
                                                   const int n4) {
    const int i = blockIdx.x * 256 + threadIdx.x;
    if (i >= n4) return;
    const float4 v = ((const float4*)in)[i];
    ushort4 o;
    o.x = f2b(v.x); o.y = f2b(v.y); o.z = f2b(v.z); o.w = f2b(v.w);
    ((ushort4*)out)[i] = o;
}

// ===========================================================================
// Gather: ONE WAVE PER ROW (50000 waves, grid 12500x256) -> every row's load
// batch is concurrently in flight; no per-wave row serialization (round-9:
// 4096 waves x ~12 rows each = grid-starved at 32% occupancy).
// Deg-adaptive single-drain batches: <=16 / <=32 / loop.
// z = scl.*(h_self + sum_nbr h) + (deg+1).*sft  (ss precomputed by finalize)
// ===========================================================================
__global__ __launch_bounds__(256, 4) void gather_kernel(const unsigned short* __restrict__ hin,
                                                        const int* __restrict__ rowptr,
                                                        const int* __restrict__ col,
                                                        const float* __restrict__ ss,
                                                        const int apply,
                                                        float* __restrict__ z) {
    const int wv = (blockIdx.x * 256 + threadIdx.x) >> 6;
    const int lane = threadIdx.x & 63;
    const int row = rfl(wv);
    if (row >= NN) return;
    const float scl = apply ? ss[lane] : 1.0f;
    const float sft = apply ? ss[64 + lane] : 0.0f;

    const int beg = rfl(rowptr[row]);
    const int end = rfl(rowptr[row + 1]);
    const int deg = end - beg;
    float a[8];
    #pragma unroll
    for (int i = 0; i < 8; ++i) a[i] = 0.f;
    a[0] = b2f(hin[row * 64 + lane]);   // self term

    if (deg <= 16) {
        const int safeb = (beg < EE) ? beg : 0;
        int c[16];
        #pragma unroll
        for (int i = 0; i < 16; ++i) {
            const int jj = (i < deg) ? (beg + i) : safeb;
            c[i] = rfl(col[jj]);
        }
        float hv[16];
        #pragma unroll
        for (int i = 0; i < 16; ++i) hv[i] = b2f(hin[c[i] * 64 + lane]);
        #pragma unroll
        for (int i = 0; i < 16; ++i) a[i & 7] += (i < deg) ? hv[i] : 0.f;
    } else if (deg <= 32) {
        const int safeb = beg;
        int c[32];
        #pragma unroll
        for (int i = 0; i < 32; ++i) {
            const int jj = (i < deg) ? (beg + i) : safeb;
            c[i] = rfl(col[jj]);
        }
        float hv[32];
        #pragma unroll
        for (int i = 0; i < 32; ++i) hv[i] = b2f(hin[c[i] * 64 + lane]);
        #pragma unroll
        for (int i = 0; i < 32; ++i) a[i & 7] += (i < deg) ? hv[i] : 0.f;
    } else {
        int j = beg;
        for (; j + 16 <= end; j += 16) {
            int c[16];
            #pragma unroll
            for (int i = 0; i < 16; ++i) c[i] = rfl(col[j + i]);
            float hv[16];
            #pragma unroll
            for (int i = 0; i < 16; ++i) hv[i] = b2f(hin[c[i] * 64 + lane]);
            #pragma unroll
            for (int i = 0; i < 16; ++i) a[i & 7] += hv[i];
        }
        if (j < end) {
            int c[16];
            #pragma unroll
            for (int i = 0; i < 16; ++i) {
                const int jj = (j + i < end) ? (j + i) : beg;
                c[i] = rfl(col[jj]);
            }
            float hv[16];
            #pragma unroll
            for (int i = 0; i < 16; ++i) hv[i] = b2f(hin[c[i] * 64 + lane]);
            #pragma unroll
            for (int i = 0; i < 16; ++i) a[i & 7] += (j + i < end) ? hv[i] : 0.f;
        }
    }
    const float sum = ((a[0] + a[1]) + (a[2] + a[3])) + ((a[4] + a[5]) + (a[6] + a[7]));
    z[row * 64 + lane] = fmaf(sum, scl, (float)(deg + 1) * sft);
}

// ===========================================================================
// MLP: 64-row tile, 512 threads (8 waves). f0 wave-uniform -> s_load weights.
// ===========================================================================
__global__ __launch_bounds__(512) void mlp_kernel(const float* __restrict__ z,
                                                  const float* __restrict__ wa,
                                                  const float* __restrict__ ba,
                                                  const float* __restrict__ wb,
                                                  const float* __restrict__ bb,
                                                  unsigned short* __restrict__ tout,
                                                  float* __restrict__ stats) {
    __shared__ float tile[64 * TS];
    __shared__ float tile2[64 * TS];
    __shared__ float red[8][128];

    const int wave = threadIdx.x >> 6;
    const int lane = threadIdx.x & 63;
    const int row0 = blockIdx.x * 64;
    const int nrows = min(64, NN - row0);

    // ---- p0: stage z tile ----
    #pragma unroll
    for (int m = 0; m < 2; ++m) {
        const int g = m * 512 + threadIdx.x;    // 1024 float4 groups
        const int r = g >> 4;
        const int f = (g & 15) * 4;
        const int grow = row0 + r;
        float4 v = make_float4(0.f, 0.f, 0.f, 0.f);
        if (grow < NN) v = *(const float4*)(z + grow * 64 + f);
        *(float4*)(&tile[r * TS + f]) = v;
    }
    __syncthreads();

    // ---- p1: A-matmul, lane = row, wave owns features f0..f0+7 ----
    const int f0 = rfl(wave * 8);   // provably uniform -> s_load weights
    float acc[8];
    #pragma unroll
    for (int j = 0; j < 8; ++j) acc[j] = ba[f0 + j];
    #pragma unroll 4
    for (int k4 = 0; k4 < 16; ++k4) {
        const float4 v = *(const float4*)(&tile[lane * TS + k4 * 4]);
        #pragma unroll
        for (int j = 0; j < 8; ++j) {
            acc[j] = fmaf(v.x, wa[(k4 * 4 + 0) * 64 + f0 + j], acc[j]);
            acc[j] = fmaf(v.y, wa[(k4 * 4 + 1) * 64 + f0 + j], acc[j]);
            acc[j] = fmaf(v.z, wa[(k4 * 4 + 2) * 64 + f0 + j], acc[j]);
            acc[j] = fmaf(v.w, wa[(k4 * 4 + 3) * 64 + f0 + j], acc[j]);
        }
    }
    #pragma unroll
    for (int j = 0; j < 8; j += 4) {
        float4 o;
        o.x = fmaxf(acc[j + 0], 0.f);
        o.y = fmaxf(acc[j + 1], 0.f);
        o.z = fmaxf(acc[j + 2], 0.f);
        o.w = fmaxf(acc[j + 3], 0.f);
        *(float4*)(&tile2[lane * TS + f0 + j]) = o;
    }
    __syncthreads();

    // ---- p2: B-matmul -> raw t into tile ----
    #pragma unroll
    for (int j = 0; j < 8; ++j) acc[j] = bb[f0 + j];
    #pragma unroll 4
    for (int k4 = 0; k4 < 16; ++k4) {
        const float4 v = *(const float4*)(&tile2[lane * TS + k4 * 4]);
        #pragma unroll
        for (int j = 0; j < 8; ++j) {
            acc[j] = fmaf(v.x, wb[(k4 * 4 + 0) * 64 + f0 + j], acc[j]);
            acc[j] = fmaf(v.y, wb[(k4 * 4 + 1) * 64 + f0 + j], acc[j]);
            acc[j] = fmaf(v.z, wb[(k4 * 4 + 2) * 64 + f0 + j], acc[j]);
            acc[j] = fmaf(v.w, wb[(k4 * 4 + 3) * 64 + f0 + j], acc[j]);
        }
    }
    #pragma unroll
    for (int j = 0; j < 8; j += 4) {
        float4 o;
        o.x = fmaxf(acc[j + 0], 0.f);
        o.y = fmaxf(acc[j + 1], 0.f);
        o.z = fmaxf(acc[j + 2], 0.f);
        o.w = fmaxf(acc[j + 3], 0.f);
        *(float4*)(&tile[lane * TS + f0 + j]) = o;
    }
    __syncthreads();

    // ---- p3a: BN partials ----
    {
        const int rbeg = wave * 8;
        const int rend = min(rbeg + 8, nrows);
        float s = 0.f, sq = 0.f;
        for (int r = rbeg; r < rend; ++r) {
            const float v = tile[r * TS + lane];
            s += v;
            sq += v * v;
        }
        red[wave][lane] = s;
        red[wave][64 + lane] = sq;
    }
    __syncthreads();
    if (threadIdx.x < 128) {
        float tot = 0.f;
        #pragma unroll
        for (int w = 0; w < 8; ++w) tot += red[w][threadIdx.x];
        atomicAdd(&stats[(blockIdx.x & 7) * 128 + threadIdx.x], tot);
    }

    // ---- p3b: bf16 writeback ----
    #pragma unroll
    for (int m = 0; m < 2; ++m) {
        const int g = m * 512 + threadIdx.x;
        const int r = g >> 4;
        const int f = (g & 15) * 4;
        const int grow = row0 + r;
        if (grow < NN) {
            const float4 v = *(const float4*)(&tile[r * TS + f]);
            ushort4 o;
            o.x = f2b(v.x); o.y = f2b(v.y); o.z = f2b(v.z); o.w = f2b(v.w);
            *(ushort4*)(tout + grow * 64 + f) = o;
        }
    }
}

// ===========================================================================
// stats[8][128] -> fused BN scale/shift (tiny; keeps gather preamble at 2 loads)
// ===========================================================================
__global__ __launch_bounds__(128) void finalize_kernel(const float* __restrict__ stats,
                                                       const float* __restrict__ g,
                                                       const float* __restrict__ be,
                                                       float* __restrict__ ss) {
    __shared__ float red[128];
    const int f = threadIdx.x;
    float tot = 0.f;
    #pragma unroll
    for (int k = 0; k < 8; ++k) tot += stats[k * 128 + f];
    red[f] = tot;
    __syncthreads();
    if (f < 64) {
        const float mean = red[f] * (1.0f / NN);
        const float var = red[64 + f] * (1.0f / NN) - mean * mean;
        const float scl = g[f] * rsqrtf(var + 1e-5f);
        ss[f] = scl;
        ss[64 + f] = be[f] - mean * scl;
    }
}

// ===========================================================================
// Pool (bf16 t in, layer-3 affine from ss); batch sorted -> boundary atomics.
// ===========================================================================
__global__ __launch_bounds__(256) void pool_kernel(const unsigned short* __restrict__ t,
                                                   const int* __restrict__ batch,
                                                   const float* __restrict__ ss,
                                                   float* __restrict__ xpool) {
    const int wv = (blockIdx.x * 256 + threadIdx.x) >> 6;
    const int lane = threadIdx.x & 63;
    const int r0 = wv * 64;
    if (r0 >= NN) return;
    const int r1 = min(r0 + 64, NN);
    const float scl = ss[lane];
    const float sft = ss[64 + lane];
    int gprev = batch[r0];
    float acc = 0.f;
    for (int r = r0; r < r1; ++r) {
        const int g = batch[r];
        if (g != gprev) {
            __hip_atomic_fetch_add(&xpool[gprev * 64 + lane], acc,
                                   __ATOMIC_RELAXED, __HIP_MEMORY_SCOPE_AGENT);
            acc = 0.f;
            gprev = g;
        }
        acc += fmaf(b2f(t[r * 64 + lane]), scl, sft);
    }
    __hip_atomic_fetch_add(&xpool[gprev * 64 + lane], acc,
                           __ATOMIC_RELAXED, __HIP_MEMORY_SCOPE_AGENT);
}

// ===========================================================================
// Fused head: out[g] = relu((xpool[g] @ w0 + b0) @ w1 + b1). One block per g.
// ===========================================================================
__global__ __launch_bounds__(128) void head_kernel(const float* __restrict__ xpool,
                                                   const float* __restrict__ w0,
                                                   const float* __restrict__ b0,
                                                   const float* __restrict__ w1,
                                                   const float* __restrict__ b1,
                                                   float* __restrict__ out) {
    __shared__ float xp[64];
    __shared__ float midl[128];
    const int g = blockIdx.x;
    const int t = threadIdx.x;
    if (t < 64) xp[t] = xpool[g * 64 + t];
    __syncthreads();
    float acc = b0[t];
    #pragma unroll 8
    for (int k = 0; k < 64; ++k) acc = fmaf(xp[k], w0[k * 128 + t], acc);
    midl[t] = acc;
    __syncthreads();
    if (t < 64) {
        float a2 = b1[t];
        #pragma unroll 8
        for (int k = 0; k < 128; ++k) a2 = fmaf(midl[k], w1[k * 64 + t], a2);
        out[g * 64 + t] = fmaxf(a2, 0.f);
    }
}

extern "C" void kernel_launch(void* const* d_in, const int* in_sizes, int n_in,
                              void* d_out, int out_size, void* d_ws, size_t ws_size,
                              hipStream_t stream) {
    const float* x = (const float*)d_in[0];
    const int* ei = (const int*)d_in[1];
    const int* batch = (const int*)d_in[2];

    // ---- workspace layout ----
    int* ibase   = (int*)d_ws;
    int* counts  = ibase;            // 50000
    int* scanned = ibase + 50000;    // 50000
    int* rowptr  = ibase + 100000;   // 50001 (pad to 50004)
    int* cursor  = ibase + 150004;   // 50000
    int* bsum    = ibase + 200004;   // 128 (98 used)
    int* col     = ibase + 200132;   // 800000 -> int end 1,000,132 (pad 1,000,192)
    float* fbase = (float*)d_ws + 1000192;       // 16B aligned
    float* stats = fbase;                        // 3 x 1024 = 3072
    float* xpool = stats + 3072;                 // 32768
    float* ss    = xpool + 32768;                // 128
    float* z     = ss + 128;                     // NN*64 = 3,200,000 fp32
    unsigned short* xbf  = (unsigned short*)(z + 3200000);  // 3.2M ushorts
    unsigned short* t0bf = xbf + 3200000;
    unsigned short* t1bf = t0bf + 3200000;

    // ---- CSR build + zeroing ----
    hipMemsetAsync(counts, 0, 50000 * sizeof(int), stream);
    hipMemsetAsync(stats, 0, (3072 + 32768) * sizeof(float), stream);  // stats + xpool
    hist_kernel<<<(EE + 255) / 256, 256, 0, stream>>>(ei, counts);
    scan1_kernel<<<SCAN_BLOCKS, 512, 0, stream>>>(counts, scanned, bsum);
    scan2_kernel<<<SCAN_BLOCKS, 512, 0, stream>>>(scanned, bsum, rowptr, cursor);
    fill_kernel<<<2048, 256, 0, stream>>>(ei, cursor, col);
    tobf_kernel<<<(800000 + 255) / 256, 256, 0, stream>>>(x, xbf, 800000);

    // ---- 3 GIN layers: gather (1 wave/row) + mlp + finalize(next ss) ----
    const unsigned short* hcur = xbf;
    unsigned short* touts[3] = {t0bf, t1bf, t0bf};
    for (int l = 0; l < 3; ++l) {
        const float* wa = (const float*)d_in[3 + l * 6 + 0];
        const float* ba = (const float*)d_in[3 + l * 6 + 1];
        const float* wb = (const float*)d_in[3 + l * 6 + 2];
        const float* bb = (const float*)d_in[3 + l * 6 + 3];
        const float* ga = (const float*)d_in[3 + l * 6 + 4];
        const float* be = (const float*)d_in[3 + l * 6 + 5];

        gather_kernel<<<12500, 256, 0, stream>>>(hcur, rowptr, col, ss, l > 0, z);
        mlp_kernel<<<TILES, 512, 0, stream>>>(z, wa, ba, wb, bb, touts[l],
                                              stats + l * 1024);
        finalize_kernel<<<1, 128, 0, stream>>>(stats + l * 1024, ga, be, ss);
        hcur = touts[l];
    }

    pool_kernel<<<(TILES + 3) / 4, 256, 0, stream>>>(t0bf, batch, ss, xpool);
    head_kernel<<<GG, 128, 0, stream>>>(
        xpool, (const float*)d_in[21], (const float*)d_in[22],
        (const float*)d_in[23], (const float*)d_in[24], (float*)d_out);
}